// Round 10
// baseline (370.660 us; speedup 1.0000x reference)
//
#include <hip/hip_runtime.h>
#include <hip/hip_bf16.h>
#include <math.h>

#define B_SZ   1024
#define CIN    96
#define COUT   12
#define LSEQ   32
#define DM     128
#define D_IN   256
#define D_ST   16
#define NH     8
#define HD     32
#define CONVD  288
#define EPROJ  552
#define EPSV   1e-5f

#define THREADS 512

typedef unsigned short ushort_t;
typedef unsigned int uint_t;
typedef __attribute__((ext_vector_type(8))) short short8;
typedef __attribute__((ext_vector_type(4))) float f32x4;
typedef __attribute__((ext_vector_type(16))) float f32x16;

// ---- fragment-packed bf16 weights (device globals, rewritten each call) ----
#define NIP (4*35*4*512)   // in_proj: 4 layers x 35 ntiles x 4 kchunks x 512
#define NOP (4*8*8*512)    // out_proj: 4 x 8 x 8 x 512
#define NFC (8*3*512)      // fc_in:   8 ntiles x 3 kchunks x 512
__device__ ushort_t g_wip[NIP];
__device__ ushort_t g_wop[NOP];
__device__ ushort_t g_wfc[NFC];

// HW RNE bf16 conversion: D[15:0]=bf16(lo), D[31:16]=bf16(hi). 1 VALU instr.
__device__ __forceinline__ uint_t cvt2bf(float lo, float hi) {
    uint_t r;
    asm("v_cvt_pk_bf16_f32 %0, %1, %2" : "=v"(r) : "v"(lo), "v"(hi));
    return r;
}
__device__ __forceinline__ ushort_t f2bf(float f) {
    return (ushort_t)cvt2bf(f, f);
}
__device__ __forceinline__ float bf2f(ushort_t u) {
    return __uint_as_float((uint_t)u << 16);
}
__device__ __forceinline__ float siluf(float v) { return v / (1.f + __expf(-v)); }
__device__ __forceinline__ float softplusf_(float v) {
    return (v > 20.f) ? v : log1pf(__expf(v));
}

// prep kernel keeps the bit-exact software RNE (not perf-critical)
__device__ __forceinline__ ushort_t f2bf_sw(float f) {
    uint_t u = __float_as_uint(f);
    u += 0x7FFFu + ((u >> 16) & 1u);
    return (ushort_t)(u >> 16);
}

__global__ void prep_weights(const float* __restrict__ in_proj_w,
                             const float* __restrict__ out_proj_w,
                             const float* __restrict__ fc_in_w) {
    int idx = blockIdx.x * 256 + threadIdx.x;
    if (idx < NIP) {
        int f = idx >> 9, r = idx & 511;
        int l = r >> 3, j = r & 7;
        int li = f / 140, rem = f - li * 140;
        int nt = rem >> 2, kc = rem & 3;
        int e = nt * 16 + (l & 15);
        int d = kc * 32 + ((l >> 4) << 3) + j;
        float v = (e < EPROJ) ? in_proj_w[((size_t)li * EPROJ + e) * DM + d] : 0.f;
        g_wip[idx] = f2bf_sw(v);
    } else if (idx < NIP + NOP) {
        int i2 = idx - NIP;
        int f = i2 >> 9, r = i2 & 511;
        int l = r >> 3, j = r & 7;
        int li = f >> 6, rem = f & 63;
        int nt = rem >> 3, kc = rem & 7;
        int d = nt * 16 + (l & 15);
        int e = kc * 32 + ((l >> 4) << 3) + j;
        g_wop[i2] = f2bf_sw(out_proj_w[((size_t)li * DM + d) * D_IN + e]);
    } else if (idx < NIP + NOP + NFC) {
        int i2 = idx - NIP - NOP;
        int f = i2 >> 9, r = i2 & 511;
        int l = r >> 3, j = r & 7;
        int nt = f / 3, kc = f - nt * 3;
        int d = nt * 16 + (l & 15);
        int c = kc * 32 + ((l >> 4) << 3) + j;
        g_wfc[i2] = f2bf_sw(fc_in_w[d * CIN + c]);
    }
}

// init out_y with the dir-independent bias: fc_out_b[o]*sum_t(outlin[t]) + out_lin_b
__global__ void init_out(const float* __restrict__ fc_out_b,
                         const float* __restrict__ out_lin_w,
                         const float* __restrict__ out_lin_b,
                         float* __restrict__ out_y) {
    int i = blockIdx.x * 256 + threadIdx.x;
    if (i >= B_SZ * COUT) return;
    int o = i % COUT;
    float s = 0.f;
#pragma unroll
    for (int t = 0; t < LSEQ; ++t) s += out_lin_w[t];
    out_y[i] = fc_out_b[o] * s + out_lin_b[0];
}

// ---- LDS arena (f32 words), total 18688 words = 74752 B  (2 blocks/CU) ----
#define OFF_HH   0       // f32 [32][132]
#define OFF_BUFB 4224    // bf16 [32][128] (swizzled); p_buf (8x 32x32 bf16) aliases BUFB+HNB
#define OFF_HNB  6272    // bf16 [32][128] (swizzled)
#define OFF_ZYB  8320    // bf16 [32][256] (swizzled), holds silu(z) then gated y
#define OFF_XB   12416   // bf16 [32][256]  (xs, then y in place)
#define OFF_BCF  16512   // f32 [32][36]    (pre-conv B/C staging)
#define OFF_DTA  17664   // f32 [32][8][2]  (dt, dt*a_neg) interleaved
#define OFF_BCB  18176   // bf16 [32][32]   (post-conv B|C, LINEAR layout)
#define SMEM_WORDS 18688
#define SMEM_BYTES (SMEM_WORDS * 4)

__global__ __launch_bounds__(THREADS, 4)
void mamba_fused(const float* __restrict__ x,
                 const float* __restrict__ buffer,
                 const float* __restrict__ fc_in_b,
                 const float* __restrict__ blk_norm_w,
                 const float* __restrict__ conv_w,
                 const float* __restrict__ conv_b,
                 const float* __restrict__ dt_bias,
                 const float* __restrict__ A_log,
                 const float* __restrict__ D_skip,
                 const float* __restrict__ mixer_norm_w,
                 const float* __restrict__ norm_f_w,
                 const float* __restrict__ fc_out_w,
                 const float* __restrict__ out_lin_w,
                 float* __restrict__ out_y,
                 float* __restrict__ out_buf)
{
    const int b   = blockIdx.x >> 1;
    const int dir = blockIdx.x & 1;
    const int tid = threadIdx.x;

    extern __shared__ float sm[];
    float*    s_hh  = sm + OFF_HH;
    ushort_t* s_bufb= (ushort_t*)(sm + OFF_BUFB);
    ushort_t* s_hnb = (ushort_t*)(sm + OFF_HNB);
    ushort_t* s_zyb = (ushort_t*)(sm + OFF_ZYB);
    ushort_t* s_xb  = (ushort_t*)(sm + OFF_XB);
    float*    s_bcf = sm + OFF_BCF;
    float*    s_dtA = sm + OFF_DTA;
    ushort_t* s_bcb = (ushort_t*)(sm + OFF_BCB);

    const int wid  = tid >> 6;
    const int lane = tid & 63;
    const int quad = lane >> 4;

    // ---- P1: shifted buffer -> s_bufb (bf16, swizzled); dir0 also writes out_buf ----
    {
        const float* bufp = buffer + (size_t)b * (CIN * LSEQ);
        const float* xp   = x + (size_t)b * CIN;
        float* obp        = out_buf + (size_t)b * (CIN * LSEQ);
        for (int i = tid; i < CIN * LSEQ; i += THREADS) {
            int c = i >> 5, l2 = i & 31;
            float v = (l2 < 31) ? bufp[i + 1] : xp[c];
            if (dir == 0) obp[i] = v;
            s_bufb[(l2 * 128 + c) ^ ((l2 & 7) << 3)] = f2bf(v);
        }
    }
    __syncthreads();

    // ---- fc_in via MFMA, write s_hh time-flipped for dir1 ----
    {
        int mt = wid >> 2, row = mt * 16 + (lane & 15);
        const short8* ab = (const short8*)s_bufb;
        const ushort_t* wb = g_wfc + lane * 8;
#pragma unroll
        for (int pass = 0; pass < 2; ++pass) {
            int nt = (wid & 3) + pass * 4;
            f32x4 acc = {0.f, 0.f, 0.f, 0.f};
#pragma unroll
            for (int kc = 0; kc < 3; ++kc) {
                short8 av = ab[(row * 16 + kc * 4 + quad) ^ (row & 7)];
                short8 bv = *(const short8*)(wb + (nt * 3 + kc) * 512);
                acc = __builtin_amdgcn_mfma_f32_16x16x32_bf16(av, bv, acc, 0, 0, 0);
            }
            int d = nt * 16 + (lane & 15);
            float bias = fc_in_b[d];
#pragma unroll
            for (int r = 0; r < 4; ++r) {
                int t = mt * 16 + quad * 4 + r;
                int tt = dir ? (31 - t) : t;
                s_hh[tt * 132 + d] = acc[r] + bias;
            }
        }
    }
    __syncthreads();

    for (int lyr = 0; lyr < 2; ++lyr) {
        const int li = dir * 2 + lyr;

        // (a) rmsnorm(s_hh) -> s_hnb (bf16, granule-swizzled)
        {
            int t = tid >> 4, sl = tid & 15;
            const float* row = s_hh + t * 132;
            float v[8]; float ss = 0.f;
#pragma unroll
            for (int j = 0; j < 8; ++j) { v[j] = row[sl * 8 + j]; ss += v[j] * v[j]; }
            ss += __shfl_xor(ss, 1); ss += __shfl_xor(ss, 2);
            ss += __shfl_xor(ss, 4); ss += __shfl_xor(ss, 8);
            float scale = rsqrtf(ss * (1.f / DM) + EPSV);
            const float* nw = blk_norm_w + li * DM;
            uint_t w[4];
#pragma unroll
            for (int p = 0; p < 4; ++p) {
                int d0 = sl * 8 + p * 2;
                w[p] = cvt2bf(v[p * 2] * scale * nw[d0],
                              v[p * 2 + 1] * scale * nw[d0 + 1]);
            }
            uint4 q = make_uint4(w[0], w[1], w[2], w[3]);
            ((uint4*)s_hnb)[(t * 16 + sl) ^ (t & 7)] = q;
        }
        __syncthreads();

        // (b) in_proj via MFMA -> s_zyb (silu(z)) / s_xb (x) / s_bcf (B,C) / s_dtA
        {
            int mt = wid >> 2, row = mt * 16 + (lane & 15);
            const short8* ab = (const short8*)s_hnb;
            short8 a[4];
#pragma unroll
            for (int kc = 0; kc < 4; ++kc)
                a[kc] = ab[(row * 16 + kc * 4 + quad) ^ (row & 7)];

            const ushort_t* wbase = g_wip + (size_t)li * (35 * 4 * 512) + lane * 8;
            for (int nt = wid & 3; nt < 35; nt += 4) {
                f32x4 acc = {0.f, 0.f, 0.f, 0.f};
#pragma unroll
                for (int kc = 0; kc < 4; ++kc) {
                    short8 bv = *(const short8*)(wbase + (nt * 4 + kc) * 512);
                    acc = __builtin_amdgcn_mfma_f32_16x16x32_bf16(a[kc], bv, acc, 0, 0, 0);
                }
                int e = nt * 16 + (lane & 15);
#pragma unroll
                for (int r = 0; r < 4; ++r) {
                    int t = mt * 16 + quad * 4 + r;
                    float v = acc[r];
                    if (e < D_IN) {
                        s_zyb[(t * 256 + e) ^ ((t & 7) << 3)] = f2bf(siluf(v));
                    } else if (e < 512) {
                        s_xb[t * 256 + (e - D_IN)] = f2bf(v);
                    } else if (e < 544) {
                        s_bcf[t * 36 + (e - 512)] = v;
                    } else if (e < EPROJ) {
                        int hd2 = e - 544;
                        float dtv = softplusf_(v + dt_bias[li * NH + hd2]);
                        float aneg = -__expf(A_log[li * NH + hd2]);
                        s_dtA[t * 16 + hd2 * 2]     = dtv;
                        s_dtA[t * 16 + hd2 * 2 + 1] = dtv * aneg;   // log-decay increment
                    }
                }
            }
        }
        __syncthreads();

        // (c) causal depthwise conv + silu, IN PLACE (rolling window);
        //     B/C lanes emit bf16 into s_bcb (LINEAR [t][ch])
        if (tid < CONVD) {
            const int c = tid;
            const float4 wv = *(const float4*)(conv_w + ((size_t)li * CONVD + c) * 4);
            const float bias = conv_b[li * CONVD + c];
            float w0 = 0.f, w1 = 0.f, w2 = 0.f;
            if (c < D_IN) {
#pragma unroll
                for (int t = 0; t < 32; ++t) {
                    float cur = bf2f(s_xb[t * 256 + c]);
                    float acc = bias + w0 * wv.x + w1 * wv.y + w2 * wv.z + cur * wv.w;
                    s_xb[t * 256 + c] = f2bf(siluf(acc));
                    w0 = w1; w1 = w2; w2 = cur;
                }
            } else {
                const int ch = c - D_IN;   // 0..31 = B(0..15) | C(16..31)
#pragma unroll
                for (int t = 0; t < 32; ++t) {
                    float cur = s_bcf[t * 36 + ch];
                    float acc = bias + w0 * wv.x + w1 * wv.y + w2 * wv.z + cur * wv.w;
                    s_bcb[t * 32 + ch] = f2bf(siluf(acc));
                    w0 = w1; w1 = w2; w2 = cur;
                }
            }
        }
        __syncthreads();

        // (d) chunked SSM via MFMA: Y = mask(CB^T ⊙ decay) · dtx + dsk·xs
        //     wave = head; p_buf per-head (aliases BUFB/HNB), all accesses LINEAR
        {
            const int h  = wid;
            const int tl = lane & 31;
            const int hw = lane >> 5;
            ushort_t* p_buf = (ushort_t*)(sm + OFF_BUFB) + h * 1024;

            // inclusive prefix sum S[t] = sum_{r<=t} dt[r]*a_neg  (per 32-lane group)
            float Sv = s_dtA[tl * 16 + h * 2 + 1];
#pragma unroll
            for (int k = 1; k < 32; k <<= 1) {
                int src = lane - ((tl >= k) ? k : 0);
                float v = __shfl(Sv, src);
                if (tl >= k) Sv += v;
            }

            // CB^T: one 32x32x16 MFMA (A = C[t][n], B = Bm[s][n])
            short8 cfrag = *(const short8*)(s_bcb + tl * 32 + 16 + hw * 8);
            short8 bfrag = *(const short8*)(s_bcb + tl * 32 + hw * 8);
            f32x16 p = {0.f,0.f,0.f,0.f,0.f,0.f,0.f,0.f,0.f,0.f,0.f,0.f,0.f,0.f,0.f,0.f};
            p = __builtin_amdgcn_mfma_f32_32x32x16_bf16(cfrag, bfrag, p, 0, 0, 0);

            // decay + causal mask + write P to p_buf (linear [t][s])
#pragma unroll
            for (int r = 0; r < 16; ++r) {
                const int Kr = (r & 3) + 8 * (r >> 2);
                int row = Kr + 4 * hw;                 // t index of this reg
                float Srow = __int_as_float(
                    __builtin_amdgcn_ds_bpermute(row * 4, __float_as_int(Sv)));
                float dec = __expf(Srow - Sv);         // exp(S[t]-S[s]), s = tl
                float val = (row >= tl) ? p[r] * dec : 0.f;
                p_buf[row * 32 + tl] = f2bf(val);
            }
            // wave-local LDS write->read fence (rule #18)
            asm volatile("s_waitcnt lgkmcnt(0)" ::: "memory");
            __builtin_amdgcn_sched_barrier(0);

            // PV: Y[t][p] = sum_s P[t][s] * dtx[s][h*32+p]   (2x 32x32x16 MFMA)
            f32x16 acc = {0.f,0.f,0.f,0.f,0.f,0.f,0.f,0.f,0.f,0.f,0.f,0.f,0.f,0.f,0.f,0.f};
#pragma unroll
            for (int kc = 0; kc < 2; ++kc) {
                short8 af = *(const short8*)(p_buf + tl * 32 + kc * 16 + hw * 8);
                union { uint_t u[4]; short8 v; } bu;
#pragma unroll
                for (int jj = 0; jj < 4; ++jj) {
                    int s0 = kc * 16 + hw * 8 + jj * 2;
                    float x0 = bf2f(s_xb[s0 * 256 + h * HD + tl]) * s_dtA[s0 * 16 + h * 2];
                    float x1 = bf2f(s_xb[(s0 + 1) * 256 + h * HD + tl]) * s_dtA[(s0 + 1) * 16 + h * 2];
                    bu.u[jj] = cvt2bf(x0, x1);
                }
                acc = __builtin_amdgcn_mfma_f32_32x32x16_bf16(af, bu.v, acc, 0, 0, 0);
            }

            // epilogue: y = acc + dsk*xs, written in place over xs (own head cols only)
            float dsk = D_skip[li * NH + h];
#pragma unroll
            for (int r = 0; r < 16; ++r) {
                const int Kr = (r & 3) + 8 * (r >> 2);
                int idx = (Kr + 4 * hw) * 256 + h * HD + tl;
                float y = acc[r] + dsk * bf2f(s_xb[idx]);
                s_xb[idx] = f2bf(y);
            }
        }
        __syncthreads();

        // (e) gate with pre-silu'd z + rmsnorm -> s_zyb (element-in-place)
        {
            int t = tid >> 4, sl = tid & 15;
            float g[16]; float ss = 0.f;
#pragma unroll
            for (int j = 0; j < 16; ++j) {
                int e = j * 16 + sl;
                float yv = bf2f(s_xb[t * 256 + e]);
                float zv = bf2f(s_zyb[(t * 256 + e) ^ ((t & 7) << 3)]);  // already silu(z)
                float gv = yv * zv;
                g[j] = gv; ss += gv * gv;
            }
            ss += __shfl_xor(ss, 1); ss += __shfl_xor(ss, 2);
            ss += __shfl_xor(ss, 4); ss += __shfl_xor(ss, 8);
            float scale = rsqrtf(ss * (1.f / D_IN) + EPSV);
            const float* mw = mixer_norm_w + li * D_IN;
#pragma unroll
            for (int j = 0; j < 16; ++j) {
                int e = j * 16 + sl;
                s_zyb[(t * 256 + e) ^ ((t & 7) << 3)] = f2bf(g[j] * scale * mw[e]);
            }
        }
        __syncthreads();

        // (f) out_proj via MFMA, residual accumulate into s_hh
        {
            int mt = wid >> 2, row = mt * 16 + (lane & 15);
            const short8* yb = (const short8*)s_zyb;
            const ushort_t* wb = g_wop + (size_t)li * (8 * 8 * 512) + lane * 8;
#pragma unroll
            for (int pass = 0; pass < 2; ++pass) {
                int nt = (wid & 3) + pass * 4;
                f32x4 acc = {0.f, 0.f, 0.f, 0.f};
#pragma unroll
                for (int kh = 0; kh < 2; ++kh) {
                    short8 a4[4];
#pragma unroll
                    for (int j = 0; j < 4; ++j)
                        a4[j] = yb[(row * 32 + (kh * 4 + j) * 4 + quad) ^ (row & 7)];
#pragma unroll
                    for (int j = 0; j < 4; ++j) {
                        short8 bv = *(const short8*)(wb + (nt * 8 + kh * 4 + j) * 512);
                        acc = __builtin_amdgcn_mfma_f32_16x16x32_bf16(a4[j], bv, acc, 0, 0, 0);
                    }
                }
                int d = nt * 16 + (lane & 15);
#pragma unroll
                for (int r = 0; r < 4; ++r)
                    s_hh[(mt * 16 + quad * 4 + r) * 132 + d] += acc[r];
            }
        }
        __syncthreads();
    } // lyr

    // ---- final rmsnorm(norm_f_w[dir]) IN PLACE on s_hh ----
    {
        int t = tid >> 4, sl = tid & 15;
        float* row = s_hh + t * 132;
        float v[8]; float ss = 0.f;
#pragma unroll
        for (int j = 0; j < 8; ++j) { v[j] = row[sl * 8 + j]; ss += v[j] * v[j]; }
        ss += __shfl_xor(ss, 1); ss += __shfl_xor(ss, 2);
        ss += __shfl_xor(ss, 4); ss += __shfl_xor(ss, 8);
        float scale = rsqrtf(ss * (1.f / DM) + EPSV);
        const float* nw = norm_f_w + dir * DM;
#pragma unroll
        for (int j = 0; j < 8; ++j) {
            int d = sl * 8 + j;
            row[d] = v[j] * scale * nw[d];
        }
    }
    __syncthreads();

    // ---- partial fc_out + out_lin reduction; atomicAdd into out_y ----
    if (tid < COUT * LSEQ) {
        int o = tid >> 5, t = tid & 31;          // t = local (possibly flipped) time
        int t_out = dir ? (31 - t) : t;          // global time index
        const float* wrow = fc_out_w + o * DM;
        const float* hrow = s_hh + t * 132;
        float acc = 0.f;
#pragma unroll
        for (int d = 0; d < DM; d += 4) {
            float4 wv = *(const float4*)(wrow + d);
            float4 hv = *(const float4*)(hrow + d);
            acc += hv.x * wv.x + hv.y * wv.y + hv.z * wv.z + hv.w * wv.w;
        }
        float part = acc * out_lin_w[t_out];
        part += __shfl_xor(part, 1);  part += __shfl_xor(part, 2);
        part += __shfl_xor(part, 4);  part += __shfl_xor(part, 8);
        part += __shfl_xor(part, 16);
        if (t == 0) atomicAdd(&out_y[b * COUT + o], part);
    }
}

extern "C" void kernel_launch(void* const* d_in, const int* in_sizes, int n_in,
                              void* d_out, int out_size, void* d_ws, size_t ws_size,
                              hipStream_t stream) {
    const float* x            = (const float*)d_in[0];
    const float* buffer      = (const float*)d_in[1];
    const float* fc_in_w     = (const float*)d_in[2];
    const float* fc_in_b     = (const float*)d_in[3];
    const float* blk_norm_w  = (const float*)d_in[4];
    const float* in_proj_w   = (const float*)d_in[5];
    const float* conv_w      = (const float*)d_in[6];
    const float* conv_b      = (const float*)d_in[7];
    const float* dt_bias     = (const float*)d_in[8];
    const float* A_log       = (const float*)d_in[9];
    const float* D_skip      = (const float*)d_in[10];
    const float* mixer_norm_w= (const float*)d_in[11];
    const float* out_proj_w  = (const float*)d_in[12];
    const float* norm_f_w    = (const float*)d_in[13];
    const float* fc_out_w    = (const float*)d_in[14];
    const float* fc_out_b    = (const float*)d_in[15];
    const float* out_lin_w   = (const float*)d_in[16];
    const float* out_lin_b   = (const float*)d_in[17];

    float* out_y   = (float*)d_out;
    float* out_buf = out_y + (size_t)B_SZ * COUT;

    prep_weights<<<(NIP + NOP + NFC + 255) / 256, 256, 0, stream>>>(
        in_proj_w, out_proj_w, fc_in_w);

    init_out<<<(B_SZ * COUT + 255) / 256, 256, 0, stream>>>(
        fc_out_b, out_lin_w, out_lin_b, out_y);

    (void)hipFuncSetAttribute((const void*)mamba_fused,
                              hipFuncAttributeMaxDynamicSharedMemorySize,
                              SMEM_BYTES);

    mamba_fused<<<B_SZ * 2, THREADS, SMEM_BYTES, stream>>>(
        x, buffer, fc_in_b, blk_norm_w, conv_w, conv_b,
        dt_bias, A_log, D_skip, mixer_norm_w, norm_f_w,
        fc_out_w, out_lin_w, out_y, out_buf);
}

// Round 11
// 331.718 us; speedup vs baseline: 1.1174x; 1.1174x over previous
//
#include <hip/hip_runtime.h>
#include <hip/hip_bf16.h>
#include <math.h>

#define B_SZ   1024
#define CIN    96
#define COUT   12
#define LSEQ   32
#define DM     128
#define D_IN   256
#define D_ST   16
#define NH     8
#define HD     32
#define CONVD  288
#define EPROJ  552
#define EPSV   1e-5f

#define THREADS 512

typedef unsigned short ushort_t;
typedef unsigned int uint_t;
typedef __attribute__((ext_vector_type(8))) short short8;
typedef __attribute__((ext_vector_type(4))) float f32x4;

// ---- fragment-packed bf16 weights (device globals, rewritten each call) ----
#define NIP (4*35*4*512)   // in_proj: 4 layers x 35 ntiles x 4 kchunks x 512
#define NOP (4*8*8*512)    // out_proj: 4 x 8 x 8 x 512
#define NFC (8*3*512)      // fc_in:   8 ntiles x 3 kchunks x 512
__device__ ushort_t g_wip[NIP];
__device__ ushort_t g_wop[NOP];
__device__ ushort_t g_wfc[NFC];

// HW RNE bf16 conversion: D[15:0]=bf16(lo), D[31:16]=bf16(hi). 1 VALU instr.
__device__ __forceinline__ uint_t cvt2bf(float lo, float hi) {
    uint_t r;
    asm("v_cvt_pk_bf16_f32 %0, %1, %2" : "=v"(r) : "v"(lo), "v"(hi));
    return r;
}
__device__ __forceinline__ ushort_t f2bf(float f) {
    return (ushort_t)cvt2bf(f, f);
}
__device__ __forceinline__ float bf2f(ushort_t u) {
    return __uint_as_float((uint_t)u << 16);
}
__device__ __forceinline__ float siluf(float v) { return v / (1.f + __expf(-v)); }
__device__ __forceinline__ float softplusf_(float v) {
    return (v > 20.f) ? v : log1pf(__expf(v));
}

// prep kernel keeps the bit-exact software RNE (not perf-critical)
__device__ __forceinline__ ushort_t f2bf_sw(float f) {
    uint_t u = __float_as_uint(f);
    u += 0x7FFFu + ((u >> 16) & 1u);
    return (ushort_t)(u >> 16);
}

__global__ void prep_weights(const float* __restrict__ in_proj_w,
                             const float* __restrict__ out_proj_w,
                             const float* __restrict__ fc_in_w) {
    int idx = blockIdx.x * 256 + threadIdx.x;
    if (idx < NIP) {
        int f = idx >> 9, r = idx & 511;
        int l = r >> 3, j = r & 7;
        int li = f / 140, rem = f - li * 140;
        int nt = rem >> 2, kc = rem & 3;
        int e = nt * 16 + (l & 15);
        int d = kc * 32 + ((l >> 4) << 3) + j;
        float v = (e < EPROJ) ? in_proj_w[((size_t)li * EPROJ + e) * DM + d] : 0.f;
        g_wip[idx] = f2bf_sw(v);
    } else if (idx < NIP + NOP) {
        int i2 = idx - NIP;
        int f = i2 >> 9, r = i2 & 511;
        int l = r >> 3, j = r & 7;
        int li = f >> 6, rem = f & 63;
        int nt = rem >> 3, kc = rem & 7;
        int d = nt * 16 + (l & 15);
        int e = kc * 32 + ((l >> 4) << 3) + j;
        g_wop[i2] = f2bf_sw(out_proj_w[((size_t)li * DM + d) * D_IN + e]);
    } else if (idx < NIP + NOP + NFC) {
        int i2 = idx - NIP - NOP;
        int f = i2 >> 9, r = i2 & 511;
        int l = r >> 3, j = r & 7;
        int nt = f / 3, kc = f - nt * 3;
        int d = nt * 16 + (l & 15);
        int c = kc * 32 + ((l >> 4) << 3) + j;
        g_wfc[i2] = f2bf_sw(fc_in_w[d * CIN + c]);
    }
}

// init out_y with the dir-independent bias: fc_out_b[o]*sum_t(outlin[t]) + out_lin_b
__global__ void init_out(const float* __restrict__ fc_out_b,
                         const float* __restrict__ out_lin_w,
                         const float* __restrict__ out_lin_b,
                         float* __restrict__ out_y) {
    int i = blockIdx.x * 256 + threadIdx.x;
    if (i >= B_SZ * COUT) return;
    int o = i % COUT;
    float s = 0.f;
#pragma unroll
    for (int t = 0; t < LSEQ; ++t) s += out_lin_w[t];
    out_y[i] = fc_out_b[o] * s + out_lin_b[0];
}

// ---- LDS arena (f32 words), total 19456 words = 77824 B  (2 blocks/CU) ----
#define OFF_HH   0       // f32 [32][132]
#define OFF_BUFB 4224    // bf16 [32][128] (swizzled); p_buf (8x 32x32 bf16) aliases BUFB+HNB
#define OFF_HNB  6272    // bf16 [32][128] (swizzled)
#define OFF_ZYB  8320    // bf16 [32][256] (swizzled), holds silu(z) then gated y
#define OFF_XB   12416   // bf16 [32][256]  (xs, then y in place)
#define OFF_BCF  16512   // f32 [32][36]    (pre-conv B/C staging)
#define OFF_DTA  17664   // f32 [32][8][2]  (dt, dt*a_neg) interleaved
#define OFF_BCB  18176   // bf16 [32][80]: [t][0..31]=B (n>=16 pad 0), [t][32..63]=C (pad 0)
#define SMEM_WORDS 19456
#define SMEM_BYTES (SMEM_WORDS * 4)

__global__ __launch_bounds__(THREADS, 4)
void mamba_fused(const float* __restrict__ x,
                 const float* __restrict__ buffer,
                 const float* __restrict__ fc_in_b,
                 const float* __restrict__ blk_norm_w,
                 const float* __restrict__ conv_w,
                 const float* __restrict__ conv_b,
                 const float* __restrict__ dt_bias,
                 const float* __restrict__ A_log,
                 const float* __restrict__ D_skip,
                 const float* __restrict__ mixer_norm_w,
                 const float* __restrict__ norm_f_w,
                 const float* __restrict__ fc_out_w,
                 const float* __restrict__ out_lin_w,
                 float* __restrict__ out_y,
                 float* __restrict__ out_buf)
{
    const int b   = blockIdx.x >> 1;
    const int dir = blockIdx.x & 1;
    const int tid = threadIdx.x;

    extern __shared__ float sm[];
    float*    s_hh  = sm + OFF_HH;
    ushort_t* s_bufb= (ushort_t*)(sm + OFF_BUFB);
    ushort_t* s_hnb = (ushort_t*)(sm + OFF_HNB);
    ushort_t* s_zyb = (ushort_t*)(sm + OFF_ZYB);
    ushort_t* s_xb  = (ushort_t*)(sm + OFF_XB);
    float*    s_bcf = sm + OFF_BCF;
    float*    s_dtA = sm + OFF_DTA;
    ushort_t* s_bcb = (ushort_t*)(sm + OFF_BCB);

    const int wid  = tid >> 6;
    const int lane = tid & 63;
    const int quad = lane >> 4;

    // ---- P1: shifted buffer -> s_bufb (bf16, swizzled); zero-init s_bcb pads ----
    {
        const float* bufp = buffer + (size_t)b * (CIN * LSEQ);
        const float* xp   = x + (size_t)b * CIN;
        float* obp        = out_buf + (size_t)b * (CIN * LSEQ);
        for (int i = tid; i < CIN * LSEQ; i += THREADS) {
            int c = i >> 5, l2 = i & 31;
            float v = (l2 < 31) ? bufp[i + 1] : xp[c];
            if (dir == 0) obp[i] = v;
            s_bufb[(l2 * 128 + c) ^ ((l2 & 7) << 3)] = f2bf(v);
        }
        for (int i = tid; i < 32 * 80; i += THREADS) s_bcb[i] = 0;
    }
    __syncthreads();

    // ---- fc_in via MFMA, write s_hh time-flipped for dir1 ----
    {
        int mt = wid >> 2, row = mt * 16 + (lane & 15);
        const short8* ab = (const short8*)s_bufb;
        const ushort_t* wb = g_wfc + lane * 8;
#pragma unroll
        for (int pass = 0; pass < 2; ++pass) {
            int nt = (wid & 3) + pass * 4;
            f32x4 acc = {0.f, 0.f, 0.f, 0.f};
#pragma unroll
            for (int kc = 0; kc < 3; ++kc) {
                short8 av = ab[(row * 16 + kc * 4 + quad) ^ (row & 7)];
                short8 bv = *(const short8*)(wb + (nt * 3 + kc) * 512);
                acc = __builtin_amdgcn_mfma_f32_16x16x32_bf16(av, bv, acc, 0, 0, 0);
            }
            int d = nt * 16 + (lane & 15);
            float bias = fc_in_b[d];
#pragma unroll
            for (int r = 0; r < 4; ++r) {
                int t = mt * 16 + quad * 4 + r;
                int tt = dir ? (31 - t) : t;
                s_hh[tt * 132 + d] = acc[r] + bias;
            }
        }
    }
    __syncthreads();

    for (int lyr = 0; lyr < 2; ++lyr) {
        const int li = dir * 2 + lyr;

        // (a) rmsnorm(s_hh) -> s_hnb (bf16, granule-swizzled)
        {
            int t = tid >> 4, sl = tid & 15;
            const float* row = s_hh + t * 132;
            float v[8]; float ss = 0.f;
#pragma unroll
            for (int j = 0; j < 8; ++j) { v[j] = row[sl * 8 + j]; ss += v[j] * v[j]; }
            ss += __shfl_xor(ss, 1); ss += __shfl_xor(ss, 2);
            ss += __shfl_xor(ss, 4); ss += __shfl_xor(ss, 8);
            float scale = rsqrtf(ss * (1.f / DM) + EPSV);
            const float* nw = blk_norm_w + li * DM;
            uint_t w[4];
#pragma unroll
            for (int p = 0; p < 4; ++p) {
                int d0 = sl * 8 + p * 2;
                w[p] = cvt2bf(v[p * 2] * scale * nw[d0],
                              v[p * 2 + 1] * scale * nw[d0 + 1]);
            }
            uint4 q = make_uint4(w[0], w[1], w[2], w[3]);
            ((uint4*)s_hnb)[(t * 16 + sl) ^ (t & 7)] = q;
        }
        __syncthreads();

        // (b) in_proj via MFMA -> s_zyb (silu(z)) / s_xb (x) / s_bcf (B,C) / s_dtA
        {
            int mt = wid >> 2, row = mt * 16 + (lane & 15);
            const short8* ab = (const short8*)s_hnb;
            short8 a[4];
#pragma unroll
            for (int kc = 0; kc < 4; ++kc)
                a[kc] = ab[(row * 16 + kc * 4 + quad) ^ (row & 7)];

            const ushort_t* wbase = g_wip + (size_t)li * (35 * 4 * 512) + lane * 8;
            for (int nt = wid & 3; nt < 35; nt += 4) {
                f32x4 acc = {0.f, 0.f, 0.f, 0.f};
#pragma unroll
                for (int kc = 0; kc < 4; ++kc) {
                    short8 bv = *(const short8*)(wbase + (nt * 4 + kc) * 512);
                    acc = __builtin_amdgcn_mfma_f32_16x16x32_bf16(a[kc], bv, acc, 0, 0, 0);
                }
                int e = nt * 16 + (lane & 15);
#pragma unroll
                for (int r = 0; r < 4; ++r) {
                    int t = mt * 16 + quad * 4 + r;
                    float v = acc[r];
                    if (e < D_IN) {
                        s_zyb[(t * 256 + e) ^ ((t & 7) << 3)] = f2bf(siluf(v));
                    } else if (e < 512) {
                        s_xb[t * 256 + (e - D_IN)] = f2bf(v);
                    } else if (e < 544) {
                        s_bcf[t * 36 + (e - 512)] = v;
                    } else if (e < EPROJ) {
                        int hd2 = e - 544;
                        float dtv = softplusf_(v + dt_bias[li * NH + hd2]);
                        float aneg = -__expf(A_log[li * NH + hd2]);
                        s_dtA[t * 16 + hd2 * 2]     = dtv;
                        s_dtA[t * 16 + hd2 * 2 + 1] = dtv * aneg;   // log-decay increment
                    }
                }
            }
        }
        __syncthreads();

        // (c) causal depthwise conv + silu, IN PLACE (rolling window);
        //     B/C lanes emit bf16 into padded s_bcb [t][80]
        if (tid < CONVD) {
            const int c = tid;
            const float4 wv = *(const float4*)(conv_w + ((size_t)li * CONVD + c) * 4);
            const float bias = conv_b[li * CONVD + c];
            float w0 = 0.f, w1 = 0.f, w2 = 0.f;
            if (c < D_IN) {
#pragma unroll
                for (int t = 0; t < 32; ++t) {
                    float cur = bf2f(s_xb[t * 256 + c]);
                    float acc = bias + w0 * wv.x + w1 * wv.y + w2 * wv.z + cur * wv.w;
                    s_xb[t * 256 + c] = f2bf(siluf(acc));
                    w0 = w1; w1 = w2; w2 = cur;
                }
            } else {
                const int ch = c - D_IN;   // 0..15 = B, 16..31 = C
                const int dst = (ch < 16) ? ch : (ch + 16);   // B at [0..15], C at [32..47]
#pragma unroll
                for (int t = 0; t < 32; ++t) {
                    float cur = s_bcf[t * 36 + ch];
                    float acc = bias + w0 * wv.x + w1 * wv.y + w2 * wv.z + cur * wv.w;
                    s_bcb[t * 80 + dst] = f2bf(siluf(acc));
                    w0 = w1; w1 = w2; w2 = cur;
                }
            }
        }
        __syncthreads();

        // (d) chunked SSM via 16x16x32 MFMAs (f32x4 accs — low register pressure)
        //     wave = head; p_buf per-head (aliases BUFB/HNB), linear [t][s]
        {
            const int h   = wid;
            const int col = lane & 15;
            const int tl  = lane & 31;
            ushort_t* p_buf = (ushort_t*)(sm + OFF_BUFB) + h * 1024;

            // inclusive prefix sum S[t] = sum_{r<=t} dt[r]*a_neg (lanes 0..31, hi replicates)
            float Sv = s_dtA[tl * 16 + h * 2 + 1];
#pragma unroll
            for (int k = 1; k < 32; k <<= 1) {
                int src = lane - ((tl >= k) ? k : 0);
                float v = __shfl(Sv, src);
                if (tl >= k) Sv += v;
            }

            // zero-fill the fully-masked (t<16, s>=16) tile of p_buf
#pragma unroll
            for (int r = 0; r < 4; ++r)
                p_buf[(quad * 4 + r) * 32 + 16 + col] = 0;

            // CB^T tiles: (tt,ss) in {(0,0),(16,0),(16,16)}; K=32 (n 16..31 zero-padded)
#pragma unroll
            for (int ti = 0; ti < 3; ++ti) {
                const int tt = (ti == 0) ? 0 : 16;
                const int ss = (ti == 2) ? 16 : 0;
                short8 cfrag = *(const short8*)(s_bcb + (tt + col) * 80 + 32 + quad * 8);
                short8 bfrag = *(const short8*)(s_bcb + (ss + col) * 80 + quad * 8);
                f32x4 p = {0.f, 0.f, 0.f, 0.f};
                p = __builtin_amdgcn_mfma_f32_16x16x32_bf16(cfrag, bfrag, p, 0, 0, 0);
                // decay + causal mask; D: row(t_loc)=quad*4+r, col(s_loc)=col
                float S_s = __int_as_float(
                    __builtin_amdgcn_ds_bpermute((ss + col) * 4, __float_as_int(Sv)));
#pragma unroll
                for (int r = 0; r < 4; ++r) {
                    int t_loc = quad * 4 + r;
                    float S_t = __int_as_float(
                        __builtin_amdgcn_ds_bpermute((tt + t_loc) * 4, __float_as_int(Sv)));
                    float dec = __expf(S_t - S_s);
                    float val = (ti == 1 || t_loc >= col) ? p[r] * dec : 0.f;
                    p_buf[(tt + t_loc) * 32 + ss + col] = f2bf(val);
                }
            }
            // wave-local LDS write->read fence (rule #18)
            asm volatile("s_waitcnt lgkmcnt(0)" ::: "memory");
            __builtin_amdgcn_sched_barrier(0);

            // PV: build both dtx B-frags FIRST (read-before-write on s_xb), then 2x2 tiles
            union { uint_t u[4]; short8 v; } bu0, bu16;
#pragma unroll
            for (int jj = 0; jj < 4; ++jj) {
                int k0 = quad * 8 + jj * 2;
                float d0 = s_dtA[k0 * 16 + h * 2];
                float d1 = s_dtA[(k0 + 1) * 16 + h * 2];
                bu0.u[jj]  = cvt2bf(bf2f(s_xb[k0 * 256 + h * HD + col]) * d0,
                                    bf2f(s_xb[(k0 + 1) * 256 + h * HD + col]) * d1);
                bu16.u[jj] = cvt2bf(bf2f(s_xb[k0 * 256 + h * HD + 16 + col]) * d0,
                                    bf2f(s_xb[(k0 + 1) * 256 + h * HD + 16 + col]) * d1);
            }
            float dsk = D_skip[li * NH + h];
#pragma unroll
            for (int tt = 0; tt < 32; tt += 16) {
                short8 af = *(const short8*)(p_buf + (tt + col) * 32 + quad * 8);
                f32x4 acc0 = {0.f, 0.f, 0.f, 0.f};
                f32x4 acc1 = {0.f, 0.f, 0.f, 0.f};
                acc0 = __builtin_amdgcn_mfma_f32_16x16x32_bf16(af, bu0.v,  acc0, 0, 0, 0);
                acc1 = __builtin_amdgcn_mfma_f32_16x16x32_bf16(af, bu16.v, acc1, 0, 0, 0);
#pragma unroll
                for (int r = 0; r < 4; ++r) {
                    int t = tt + quad * 4 + r;
                    int i0 = t * 256 + h * HD + col;
                    int i1 = i0 + 16;
                    s_xb[i0] = f2bf(acc0[r] + dsk * bf2f(s_xb[i0]));
                    s_xb[i1] = f2bf(acc1[r] + dsk * bf2f(s_xb[i1]));
                }
            }
        }
        __syncthreads();

        // (e) gate with pre-silu'd z + rmsnorm -> s_zyb (element-in-place)
        {
            int t = tid >> 4, sl = tid & 15;
            float g[16]; float ss = 0.f;
#pragma unroll
            for (int j = 0; j < 16; ++j) {
                int e = j * 16 + sl;
                float yv = bf2f(s_xb[t * 256 + e]);
                float zv = bf2f(s_zyb[(t * 256 + e) ^ ((t & 7) << 3)]);  // already silu(z)
                float gv = yv * zv;
                g[j] = gv; ss += gv * gv;
            }
            ss += __shfl_xor(ss, 1); ss += __shfl_xor(ss, 2);
            ss += __shfl_xor(ss, 4); ss += __shfl_xor(ss, 8);
            float scale = rsqrtf(ss * (1.f / D_IN) + EPSV);
            const float* mw = mixer_norm_w + li * D_IN;
#pragma unroll
            for (int j = 0; j < 16; ++j) {
                int e = j * 16 + sl;
                s_zyb[(t * 256 + e) ^ ((t & 7) << 3)] = f2bf(g[j] * scale * mw[e]);
            }
        }
        __syncthreads();

        // (f) out_proj via MFMA, residual accumulate into s_hh
        {
            int mt = wid >> 2, row = mt * 16 + (lane & 15);
            const short8* yb = (const short8*)s_zyb;
            const ushort_t* wb = g_wop + (size_t)li * (8 * 8 * 512) + lane * 8;
#pragma unroll
            for (int pass = 0; pass < 2; ++pass) {
                int nt = (wid & 3) + pass * 4;
                f32x4 acc = {0.f, 0.f, 0.f, 0.f};
#pragma unroll
                for (int kh = 0; kh < 2; ++kh) {
                    short8 a4[4];
#pragma unroll
                    for (int j = 0; j < 4; ++j)
                        a4[j] = yb[(row * 32 + (kh * 4 + j) * 4 + quad) ^ (row & 7)];
#pragma unroll
                    for (int j = 0; j < 4; ++j) {
                        short8 bv = *(const short8*)(wb + (nt * 8 + kh * 4 + j) * 512);
                        acc = __builtin_amdgcn_mfma_f32_16x16x32_bf16(a4[j], bv, acc, 0, 0, 0);
                    }
                }
                int d = nt * 16 + (lane & 15);
#pragma unroll
                for (int r = 0; r < 4; ++r)
                    s_hh[(mt * 16 + quad * 4 + r) * 132 + d] += acc[r];
            }
        }
        __syncthreads();
    } // lyr

    // ---- final rmsnorm(norm_f_w[dir]) IN PLACE on s_hh ----
    {
        int t = tid >> 4, sl = tid & 15;
        float* row = s_hh + t * 132;
        float v[8]; float ss = 0.f;
#pragma unroll
        for (int j = 0; j < 8; ++j) { v[j] = row[sl * 8 + j]; ss += v[j] * v[j]; }
        ss += __shfl_xor(ss, 1); ss += __shfl_xor(ss, 2);
        ss += __shfl_xor(ss, 4); ss += __shfl_xor(ss, 8);
        float scale = rsqrtf(ss * (1.f / DM) + EPSV);
        const float* nw = norm_f_w + dir * DM;
#pragma unroll
        for (int j = 0; j < 8; ++j) {
            int d = sl * 8 + j;
            row[d] = v[j] * scale * nw[d];
        }
    }
    __syncthreads();

    // ---- partial fc_out + out_lin reduction; atomicAdd into out_y ----
    if (tid < COUT * LSEQ) {
        int o = tid >> 5, t = tid & 31;          // t = local (possibly flipped) time
        int t_out = dir ? (31 - t) : t;          // global time index
        const float* wrow = fc_out_w + o * DM;
        const float* hrow = s_hh + t * 132;
        float acc = 0.f;
#pragma unroll
        for (int d = 0; d < DM; d += 4) {
            float4 wv = *(const float4*)(wrow + d);
            float4 hv = *(const float4*)(hrow + d);
            acc += hv.x * wv.x + hv.y * wv.y + hv.z * wv.z + hv.w * wv.w;
        }
        float part = acc * out_lin_w[t_out];
        part += __shfl_xor(part, 1);  part += __shfl_xor(part, 2);
        part += __shfl_xor(part, 4);  part += __shfl_xor(part, 8);
        part += __shfl_xor(part, 16);
        if (t == 0) atomicAdd(&out_y[b * COUT + o], part);
    }
}

extern "C" void kernel_launch(void* const* d_in, const int* in_sizes, int n_in,
                              void* d_out, int out_size, void* d_ws, size_t ws_size,
                              hipStream_t stream) {
    const float* x            = (const float*)d_in[0];
    const float* buffer      = (const float*)d_in[1];
    const float* fc_in_w     = (const float*)d_in[2];
    const float* fc_in_b     = (const float*)d_in[3];
    const float* blk_norm_w  = (const float*)d_in[4];
    const float* in_proj_w   = (const float*)d_in[5];
    const float* conv_w      = (const float*)d_in[6];
    const float* conv_b      = (const float*)d_in[7];
    const float* dt_bias     = (const float*)d_in[8];
    const float* A_log       = (const float*)d_in[9];
    const float* D_skip      = (const float*)d_in[10];
    const float* mixer_norm_w= (const float*)d_in[11];
    const float* out_proj_w  = (const float*)d_in[12];
    const float* norm_f_w    = (const float*)d_in[13];
    const float* fc_out_w    = (const float*)d_in[14];
    const float* fc_out_b    = (const float*)d_in[15];
    const float* out_lin_w   = (const float*)d_in[16];
    const float* out_lin_b   = (const float*)d_in[17];

    float* out_y   = (float*)d_out;
    float* out_buf = out_y + (size_t)B_SZ * COUT;

    prep_weights<<<(NIP + NOP + NFC + 255) / 256, 256, 0, stream>>>(
        in_proj_w, out_proj_w, fc_in_w);

    init_out<<<(B_SZ * COUT + 255) / 256, 256, 0, stream>>>(
        fc_out_b, out_lin_w, out_lin_b, out_y);

    (void)hipFuncSetAttribute((const void*)mamba_fused,
                              hipFuncAttributeMaxDynamicSharedMemorySize,
                              SMEM_BYTES);

    mamba_fused<<<B_SZ * 2, THREADS, SMEM_BYTES, stream>>>(
        x, buffer, fc_in_b, blk_norm_w, conv_w, conv_b,
        dt_bias, A_log, D_skip, mixer_norm_w, norm_f_w,
        fc_out_w, out_lin_w, out_y, out_buf);
}

// Round 12
// 325.803 us; speedup vs baseline: 1.1377x; 1.0182x over previous
//
#include <hip/hip_runtime.h>
#include <hip/hip_bf16.h>
#include <math.h>

#define B_SZ   1024
#define CIN    96
#define COUT   12
#define LSEQ   32
#define DM     128
#define D_IN   256
#define D_ST   16
#define NH     8
#define HD     32
#define CONVD  288
#define EPROJ  552
#define EPSV   1e-5f

#define THREADS 512

// hard scheduling fence: stop the compiler from hoisting loads/VALU across phases
#define SBAR() __builtin_amdgcn_sched_barrier(0)

typedef unsigned short ushort_t;
typedef unsigned int uint_t;
typedef __attribute__((ext_vector_type(8))) short short8;
typedef __attribute__((ext_vector_type(4))) float f32x4;

// ---- fragment-packed bf16 weights (device globals, rewritten each call) ----
#define NIP (4*35*4*512)   // in_proj: 4 layers x 35 ntiles x 4 kchunks x 512
#define NOP (4*8*8*512)    // out_proj: 4 x 8 x 8 x 512
#define NFC (8*3*512)      // fc_in:   8 ntiles x 3 kchunks x 512
__device__ ushort_t g_wip[NIP];
__device__ ushort_t g_wop[NOP];
__device__ ushort_t g_wfc[NFC];

// HW RNE bf16 conversion: D[15:0]=bf16(lo), D[31:16]=bf16(hi). 1 VALU instr.
__device__ __forceinline__ uint_t cvt2bf(float lo, float hi) {
    uint_t r;
    asm("v_cvt_pk_bf16_f32 %0, %1, %2" : "=v"(r) : "v"(lo), "v"(hi));
    return r;
}
__device__ __forceinline__ ushort_t f2bf(float f) {
    return (ushort_t)cvt2bf(f, f);
}
__device__ __forceinline__ float bf2f(ushort_t u) {
    return __uint_as_float((uint_t)u << 16);
}
__device__ __forceinline__ float siluf(float v) { return v / (1.f + __expf(-v)); }
__device__ __forceinline__ float softplusf_(float v) {
    return (v > 20.f) ? v : log1pf(__expf(v));
}
__device__ __forceinline__ float bperm(int idx, float v) {
    return __int_as_float(__builtin_amdgcn_ds_bpermute(idx * 4, __float_as_int(v)));
}

// prep kernel keeps the bit-exact software RNE (not perf-critical)
__device__ __forceinline__ ushort_t f2bf_sw(float f) {
    uint_t u = __float_as_uint(f);
    u += 0x7FFFu + ((u >> 16) & 1u);
    return (ushort_t)(u >> 16);
}

__global__ void prep_weights(const float* __restrict__ in_proj_w,
                             const float* __restrict__ out_proj_w,
                             const float* __restrict__ fc_in_w) {
    int idx = blockIdx.x * 256 + threadIdx.x;
    if (idx < NIP) {
        int f = idx >> 9, r = idx & 511;
        int l = r >> 3, j = r & 7;
        int li = f / 140, rem = f - li * 140;
        int nt = rem >> 2, kc = rem & 3;
        int e = nt * 16 + (l & 15);
        int d = kc * 32 + ((l >> 4) << 3) + j;
        float v = (e < EPROJ) ? in_proj_w[((size_t)li * EPROJ + e) * DM + d] : 0.f;
        g_wip[idx] = f2bf_sw(v);
    } else if (idx < NIP + NOP) {
        int i2 = idx - NIP;
        int f = i2 >> 9, r = i2 & 511;
        int l = r >> 3, j = r & 7;
        int li = f >> 6, rem = f & 63;
        int nt = rem >> 3, kc = rem & 7;
        int d = nt * 16 + (l & 15);
        int e = kc * 32 + ((l >> 4) << 3) + j;
        g_wop[i2] = f2bf_sw(out_proj_w[((size_t)li * DM + d) * D_IN + e]);
    } else if (idx < NIP + NOP + NFC) {
        int i2 = idx - NIP - NOP;
        int f = i2 >> 9, r = i2 & 511;
        int l = r >> 3, j = r & 7;
        int nt = f / 3, kc = f - nt * 3;
        int d = nt * 16 + (l & 15);
        int c = kc * 32 + ((l >> 4) << 3) + j;
        g_wfc[i2] = f2bf_sw(fc_in_w[d * CIN + c]);
    }
}

// init out_y with the dir-independent bias: fc_out_b[o]*sum_t(outlin[t]) + out_lin_b
__global__ void init_out(const float* __restrict__ fc_out_b,
                         const float* __restrict__ out_lin_w,
                         const float* __restrict__ out_lin_b,
                         float* __restrict__ out_y) {
    int i = blockIdx.x * 256 + threadIdx.x;
    if (i >= B_SZ * COUT) return;
    int o = i % COUT;
    float s = 0.f;
#pragma unroll
    for (int t = 0; t < LSEQ; ++t) s += out_lin_w[t];
    out_y[i] = fc_out_b[o] * s + out_lin_b[0];
}

// ---- LDS arena (f32 words), total 19456 words = 77824 B  (2 blocks/CU) ----
#define OFF_HH   0       // f32 [32][132]
#define OFF_BUFB 4224    // bf16 [32][128] (swizzled); p_buf (8x 32x32 bf16) aliases BUFB+HNB
#define OFF_HNB  6272    // bf16 [32][128] (swizzled)
#define OFF_ZYB  8320    // bf16 [32][256] (swizzled), holds silu(z) then gated y
#define OFF_XB   12416   // bf16 [32][256]  (xs, then y in place)
#define OFF_BCF  16512   // f32 [32][36]    (pre-conv B/C staging)
#define OFF_DTA  17664   // f32 [32][8][2]  (dt, dt*a_neg) interleaved
#define OFF_BCB  18176   // bf16 [32][80]: [t][0..15]=B, [t][32..47]=C, rest pad 0
#define SMEM_WORDS 19456
#define SMEM_BYTES (SMEM_WORDS * 4)

__global__ __launch_bounds__(THREADS, 4)
void mamba_fused(const float* __restrict__ x,
                 const float* __restrict__ buffer,
                 const float* __restrict__ fc_in_b,
                 const float* __restrict__ blk_norm_w,
                 const float* __restrict__ conv_w,
                 const float* __restrict__ conv_b,
                 const float* __restrict__ dt_bias,
                 const float* __restrict__ A_log,
                 const float* __restrict__ D_skip,
                 const float* __restrict__ mixer_norm_w,
                 const float* __restrict__ norm_f_w,
                 const float* __restrict__ fc_out_w,
                 const float* __restrict__ out_lin_w,
                 float* __restrict__ out_y,
                 float* __restrict__ out_buf)
{
    const int b   = blockIdx.x >> 1;
    const int dir = blockIdx.x & 1;
    const int tid = threadIdx.x;

    extern __shared__ float sm[];
    float*    s_hh  = sm + OFF_HH;
    ushort_t* s_bufb= (ushort_t*)(sm + OFF_BUFB);
    ushort_t* s_hnb = (ushort_t*)(sm + OFF_HNB);
    ushort_t* s_zyb = (ushort_t*)(sm + OFF_ZYB);
    ushort_t* s_xb  = (ushort_t*)(sm + OFF_XB);
    float*    s_bcf = sm + OFF_BCF;
    float*    s_dtA = sm + OFF_DTA;
    ushort_t* s_bcb = (ushort_t*)(sm + OFF_BCB);

    const int wid  = tid >> 6;
    const int lane = tid & 63;
    const int quad = lane >> 4;

    // ---- P1: shifted buffer -> s_bufb (bf16, swizzled); zero-init s_bcb pads ----
    {
        const float* bufp = buffer + (size_t)b * (CIN * LSEQ);
        const float* xp   = x + (size_t)b * CIN;
        float* obp        = out_buf + (size_t)b * (CIN * LSEQ);
        for (int i = tid; i < CIN * LSEQ; i += THREADS) {
            int c = i >> 5, l2 = i & 31;
            float v = (l2 < 31) ? bufp[i + 1] : xp[c];
            if (dir == 0) obp[i] = v;
            s_bufb[(l2 * 128 + c) ^ ((l2 & 7) << 3)] = f2bf(v);
        }
        for (int i = tid; i < 32 * 80; i += THREADS) s_bcb[i] = 0;
    }
    __syncthreads();
    SBAR();

    // ---- fc_in via MFMA, write s_hh time-flipped for dir1 ----
    {
        int mt = wid >> 2, row = mt * 16 + (lane & 15);
        const short8* ab = (const short8*)s_bufb;
        const ushort_t* wb = g_wfc + lane * 8;
#pragma unroll
        for (int pass = 0; pass < 2; ++pass) {
            int nt = (wid & 3) + pass * 4;
            f32x4 acc = {0.f, 0.f, 0.f, 0.f};
#pragma unroll
            for (int kc = 0; kc < 3; ++kc) {
                short8 av = ab[(row * 16 + kc * 4 + quad) ^ (row & 7)];
                short8 bv = *(const short8*)(wb + (nt * 3 + kc) * 512);
                acc = __builtin_amdgcn_mfma_f32_16x16x32_bf16(av, bv, acc, 0, 0, 0);
            }
            int d = nt * 16 + (lane & 15);
            float bias = fc_in_b[d];
#pragma unroll
            for (int r = 0; r < 4; ++r) {
                int t = mt * 16 + quad * 4 + r;
                int tt = dir ? (31 - t) : t;
                s_hh[tt * 132 + d] = acc[r] + bias;
            }
        }
    }
    __syncthreads();
    SBAR();

    for (int lyr = 0; lyr < 2; ++lyr) {
        const int li = dir * 2 + lyr;

        // (a) rmsnorm(s_hh) -> s_hnb (bf16, granule-swizzled)
        {
            int t = tid >> 4, sl = tid & 15;
            const float* row = s_hh + t * 132;
            float v[8]; float ss = 0.f;
#pragma unroll
            for (int j = 0; j < 8; ++j) { v[j] = row[sl * 8 + j]; ss += v[j] * v[j]; }
            ss += __shfl_xor(ss, 1); ss += __shfl_xor(ss, 2);
            ss += __shfl_xor(ss, 4); ss += __shfl_xor(ss, 8);
            float scale = rsqrtf(ss * (1.f / DM) + EPSV);
            const float* nw = blk_norm_w + li * DM;
            uint_t w[4];
#pragma unroll
            for (int p = 0; p < 4; ++p) {
                int d0 = sl * 8 + p * 2;
                w[p] = cvt2bf(v[p * 2] * scale * nw[d0],
                              v[p * 2 + 1] * scale * nw[d0 + 1]);
            }
            uint4 q = make_uint4(w[0], w[1], w[2], w[3]);
            ((uint4*)s_hnb)[(t * 16 + sl) ^ (t & 7)] = q;
        }
        __syncthreads();
        SBAR();

        // (b) in_proj via MFMA -> s_zyb (silu(z)) / s_xb (x) / s_bcf (B,C) / s_dtA
        {
            int mt = wid >> 2, row = mt * 16 + (lane & 15);
            const short8* ab = (const short8*)s_hnb;
            short8 a[4];
#pragma unroll
            for (int kc = 0; kc < 4; ++kc)
                a[kc] = ab[(row * 16 + kc * 4 + quad) ^ (row & 7)];

            const ushort_t* wbase = g_wip + (size_t)li * (35 * 4 * 512) + lane * 8;
            for (int nt = wid & 3; nt < 35; nt += 4) {
                f32x4 acc = {0.f, 0.f, 0.f, 0.f};
#pragma unroll
                for (int kc = 0; kc < 4; ++kc) {
                    short8 bv = *(const short8*)(wbase + (nt * 4 + kc) * 512);
                    acc = __builtin_amdgcn_mfma_f32_16x16x32_bf16(a[kc], bv, acc, 0, 0, 0);
                }
                int e = nt * 16 + (lane & 15);
#pragma unroll
                for (int r = 0; r < 4; ++r) {
                    int t = mt * 16 + quad * 4 + r;
                    float v = acc[r];
                    if (e < D_IN) {
                        s_zyb[(t * 256 + e) ^ ((t & 7) << 3)] = f2bf(siluf(v));
                    } else if (e < 512) {
                        s_xb[t * 256 + (e - D_IN)] = f2bf(v);
                    } else if (e < 544) {
                        s_bcf[t * 36 + (e - 512)] = v;
                    } else if (e < EPROJ) {
                        int hd2 = e - 544;
                        float dtv = softplusf_(v + dt_bias[li * NH + hd2]);
                        float aneg = -__expf(A_log[li * NH + hd2]);
                        s_dtA[t * 16 + hd2 * 2]     = dtv;
                        s_dtA[t * 16 + hd2 * 2 + 1] = dtv * aneg;   // log-decay increment
                    }
                }
            }
        }
        __syncthreads();
        SBAR();

        // (c) causal depthwise conv + silu, IN PLACE (rolling window);
        //     B/C lanes emit bf16 into padded s_bcb [t][80]
        if (tid < CONVD) {
            const int c = tid;
            const float4 wv = *(const float4*)(conv_w + ((size_t)li * CONVD + c) * 4);
            const float bias = conv_b[li * CONVD + c];
            float w0 = 0.f, w1 = 0.f, w2 = 0.f;
            if (c < D_IN) {
#pragma unroll
                for (int t = 0; t < 32; ++t) {
                    float cur = bf2f(s_xb[t * 256 + c]);
                    float acc = bias + w0 * wv.x + w1 * wv.y + w2 * wv.z + cur * wv.w;
                    s_xb[t * 256 + c] = f2bf(siluf(acc));
                    w0 = w1; w1 = w2; w2 = cur;
                }
            } else {
                const int ch = c - D_IN;   // 0..15 = B, 16..31 = C
                const int dst = (ch < 16) ? ch : (ch + 16);   // B at [0..15], C at [32..47]
#pragma unroll
                for (int t = 0; t < 32; ++t) {
                    float cur = s_bcf[t * 36 + ch];
                    float acc = bias + w0 * wv.x + w1 * wv.y + w2 * wv.z + cur * wv.w;
                    s_bcb[t * 80 + dst] = f2bf(siluf(acc));
                    w0 = w1; w1 = w2; w2 = cur;
                }
            }
        }
        __syncthreads();
        SBAR();

        // (d) chunked SSM via 16x16x32 MFMAs; wave = head; p_buf linear [t][s]
        {
            const int h   = wid;
            const int col = lane & 15;
            const int tl  = lane & 31;
            ushort_t* p_buf = (ushort_t*)(sm + OFF_BUFB) + h * 1024;

            // inclusive prefix sum S[t] over 32-lane groups (hi half replicates)
            float Sv = s_dtA[tl * 16 + h * 2 + 1];
#pragma unroll
            for (int k = 1; k < 32; k <<= 1) {
                int src = lane - ((tl >= k) ? k : 0);
                float v = __shfl(Sv, src);
                if (tl >= k) Sv += v;
            }
            SBAR();

            // zero the fully-masked (t<16, s>=16) block
#pragma unroll
            for (int r = 0; r < 4; ++r)
                p_buf[(quad * 4 + r) * 32 + 16 + col] = 0;

            // ---- tile (tt=0, ss=0), masked ----
            {
                short8 cfrag = *(const short8*)(s_bcb + col * 80 + 32 + quad * 8);
                short8 bfrag = *(const short8*)(s_bcb + col * 80 + quad * 8);
                f32x4 p = {0.f, 0.f, 0.f, 0.f};
                p = __builtin_amdgcn_mfma_f32_16x16x32_bf16(cfrag, bfrag, p, 0, 0, 0);
                float S_s = bperm(col, Sv);
#pragma unroll
                for (int r = 0; r < 4; ++r) {
                    int t_loc = quad * 4 + r;
                    float S_t = bperm(t_loc, Sv);
                    float val = (t_loc >= col) ? p[r] * __expf(S_t - S_s) : 0.f;
                    p_buf[t_loc * 32 + col] = f2bf(val);
                }
            }
            SBAR();
            // ---- tiles tt=16: ss=0 (unmasked) and ss=16 (masked), shared S_t ----
            {
                short8 cfrag  = *(const short8*)(s_bcb + (16 + col) * 80 + 32 + quad * 8);
                short8 bfrag0 = *(const short8*)(s_bcb + col * 80 + quad * 8);
                f32x4 p0 = {0.f, 0.f, 0.f, 0.f};
                p0 = __builtin_amdgcn_mfma_f32_16x16x32_bf16(cfrag, bfrag0, p0, 0, 0, 0);
                short8 bfrag1 = *(const short8*)(s_bcb + (16 + col) * 80 + quad * 8);
                f32x4 p1 = {0.f, 0.f, 0.f, 0.f};
                p1 = __builtin_amdgcn_mfma_f32_16x16x32_bf16(cfrag, bfrag1, p1, 0, 0, 0);
                float S_s0 = bperm(col, Sv);
                float S_s1 = bperm(16 + col, Sv);
#pragma unroll
                for (int r = 0; r < 4; ++r) {
                    int t_loc = quad * 4 + r;
                    float S_t = bperm(16 + t_loc, Sv);
                    p_buf[(16 + t_loc) * 32 + col] = f2bf(p0[r] * __expf(S_t - S_s0));
                    float v1 = (t_loc >= col) ? p1[r] * __expf(S_t - S_s1) : 0.f;
                    p_buf[(16 + t_loc) * 32 + 16 + col] = f2bf(v1);
                }
            }
            // wave-local LDS write->read fence (rule #18)
            asm volatile("s_waitcnt lgkmcnt(0)" ::: "memory");
            SBAR();

            // PV: build both dtx B-frags FIRST (read-before-write on s_xb), then tiles
            union { uint_t u[4]; short8 v; } bu0, bu16;
#pragma unroll
            for (int jj = 0; jj < 4; ++jj) {
                int k0 = quad * 8 + jj * 2;
                float d0 = s_dtA[k0 * 16 + h * 2];
                float d1 = s_dtA[(k0 + 1) * 16 + h * 2];
                bu0.u[jj]  = cvt2bf(bf2f(s_xb[k0 * 256 + h * HD + col]) * d0,
                                    bf2f(s_xb[(k0 + 1) * 256 + h * HD + col]) * d1);
                bu16.u[jj] = cvt2bf(bf2f(s_xb[k0 * 256 + h * HD + 16 + col]) * d0,
                                    bf2f(s_xb[(k0 + 1) * 256 + h * HD + 16 + col]) * d1);
            }
            SBAR();
            float dsk = D_skip[li * NH + h];
#pragma unroll
            for (int tt = 0; tt < 32; tt += 16) {
                short8 af = *(const short8*)(p_buf + (tt + col) * 32 + quad * 8);
                f32x4 acc0 = {0.f, 0.f, 0.f, 0.f};
                f32x4 acc1 = {0.f, 0.f, 0.f, 0.f};
                acc0 = __builtin_amdgcn_mfma_f32_16x16x32_bf16(af, bu0.v,  acc0, 0, 0, 0);
                acc1 = __builtin_amdgcn_mfma_f32_16x16x32_bf16(af, bu16.v, acc1, 0, 0, 0);
#pragma unroll
                for (int r = 0; r < 4; ++r) {
                    int t = tt + quad * 4 + r;
                    int i0 = t * 256 + h * HD + col;
                    int i1 = i0 + 16;
                    s_xb[i0] = f2bf(acc0[r] + dsk * bf2f(s_xb[i0]));
                    s_xb[i1] = f2bf(acc1[r] + dsk * bf2f(s_xb[i1]));
                }
                SBAR();
            }
        }
        __syncthreads();
        SBAR();

        // (e) gate with pre-silu'd z + rmsnorm -> s_zyb (element-in-place)
        {
            int t = tid >> 4, sl = tid & 15;
            float g[16]; float ss = 0.f;
#pragma unroll
            for (int j = 0; j < 16; ++j) {
                int e = j * 16 + sl;
                float yv = bf2f(s_xb[t * 256 + e]);
                float zv = bf2f(s_zyb[(t * 256 + e) ^ ((t & 7) << 3)]);  // already silu(z)
                float gv = yv * zv;
                g[j] = gv; ss += gv * gv;
            }
            ss += __shfl_xor(ss, 1); ss += __shfl_xor(ss, 2);
            ss += __shfl_xor(ss, 4); ss += __shfl_xor(ss, 8);
            float scale = rsqrtf(ss * (1.f / D_IN) + EPSV);
            const float* mw = mixer_norm_w + li * D_IN;
#pragma unroll
            for (int j = 0; j < 16; ++j) {
                int e = j * 16 + sl;
                s_zyb[(t * 256 + e) ^ ((t & 7) << 3)] = f2bf(g[j] * scale * mw[e]);
            }
        }
        __syncthreads();
        SBAR();

        // (f) out_proj via MFMA, residual accumulate into s_hh
        {
            int mt = wid >> 2, row = mt * 16 + (lane & 15);
            const short8* yb = (const short8*)s_zyb;
            const ushort_t* wb = g_wop + (size_t)li * (8 * 8 * 512) + lane * 8;
#pragma unroll
            for (int pass = 0; pass < 2; ++pass) {
                int nt = (wid & 3) + pass * 4;
                f32x4 acc = {0.f, 0.f, 0.f, 0.f};
#pragma unroll
                for (int kh = 0; kh < 2; ++kh) {
                    short8 a4[4];
#pragma unroll
                    for (int j = 0; j < 4; ++j)
                        a4[j] = yb[(row * 32 + (kh * 4 + j) * 4 + quad) ^ (row & 7)];
#pragma unroll
                    for (int j = 0; j < 4; ++j) {
                        short8 bv = *(const short8*)(wb + (nt * 8 + kh * 4 + j) * 512);
                        acc = __builtin_amdgcn_mfma_f32_16x16x32_bf16(a4[j], bv, acc, 0, 0, 0);
                    }
                    SBAR();
                }
                int d = nt * 16 + (lane & 15);
#pragma unroll
                for (int r = 0; r < 4; ++r)
                    s_hh[(mt * 16 + quad * 4 + r) * 132 + d] += acc[r];
            }
        }
        __syncthreads();
        SBAR();
    } // lyr

    // ---- final rmsnorm(norm_f_w[dir]) IN PLACE on s_hh ----
    {
        int t = tid >> 4, sl = tid & 15;
        float* row = s_hh + t * 132;
        float v[8]; float ss = 0.f;
#pragma unroll
        for (int j = 0; j < 8; ++j) { v[j] = row[sl * 8 + j]; ss += v[j] * v[j]; }
        ss += __shfl_xor(ss, 1); ss += __shfl_xor(ss, 2);
        ss += __shfl_xor(ss, 4); ss += __shfl_xor(ss, 8);
        float scale = rsqrtf(ss * (1.f / DM) + EPSV);
        const float* nw = norm_f_w + dir * DM;
#pragma unroll
        for (int j = 0; j < 8; ++j) {
            int d = sl * 8 + j;
            row[d] = v[j] * scale * nw[d];
        }
    }
    __syncthreads();
    SBAR();

    // ---- partial fc_out + out_lin reduction; atomicAdd into out_y ----
    if (tid < COUT * LSEQ) {
        int o = tid >> 5, t = tid & 31;          // t = local (possibly flipped) time
        int t_out = dir ? (31 - t) : t;          // global time index
        const float* wrow = fc_out_w + o * DM;
        const float* hrow = s_hh + t * 132;
        float acc = 0.f;
#pragma unroll
        for (int d = 0; d < DM; d += 4) {
            float4 wv = *(const float4*)(wrow + d);
            float4 hv = *(const float4*)(hrow + d);
            acc += hv.x * wv.x + hv.y * wv.y + hv.z * wv.z + hv.w * wv.w;
        }
        float part = acc * out_lin_w[t_out];
        part += __shfl_xor(part, 1);  part += __shfl_xor(part, 2);
        part += __shfl_xor(part, 4);  part += __shfl_xor(part, 8);
        part += __shfl_xor(part, 16);
        if (t == 0) atomicAdd(&out_y[b * COUT + o], part);
    }
}

extern "C" void kernel_launch(void* const* d_in, const int* in_sizes, int n_in,
                              void* d_out, int out_size, void* d_ws, size_t ws_size,
                              hipStream_t stream) {
    const float* x            = (const float*)d_in[0];
    const float* buffer      = (const float*)d_in[1];
    const float* fc_in_w     = (const float*)d_in[2];
    const float* fc_in_b     = (const float*)d_in[3];
    const float* blk_norm_w  = (const float*)d_in[4];
    const float* in_proj_w   = (const float*)d_in[5];
    const float* conv_w      = (const float*)d_in[6];
    const float* conv_b      = (const float*)d_in[7];
    const float* dt_bias     = (const float*)d_in[8];
    const float* A_log       = (const float*)d_in[9];
    const float* D_skip      = (const float*)d_in[10];
    const float* mixer_norm_w= (const float*)d_in[11];
    const float* out_proj_w  = (const float*)d_in[12];
    const float* norm_f_w    = (const float*)d_in[13];
    const float* fc_out_w    = (const float*)d_in[14];
    const float* fc_out_b    = (const float*)d_in[15];
    const float* out_lin_w   = (const float*)d_in[16];
    const float* out_lin_b   = (const float*)d_in[17];

    float* out_y   = (float*)d_out;
    float* out_buf = out_y + (size_t)B_SZ * COUT;

    prep_weights<<<(NIP + NOP + NFC + 255) / 256, 256, 0, stream>>>(
        in_proj_w, out_proj_w, fc_in_w);

    init_out<<<(B_SZ * COUT + 255) / 256, 256, 0, stream>>>(
        fc_out_b, out_lin_w, out_lin_b, out_y);

    (void)hipFuncSetAttribute((const void*)mamba_fused,
                              hipFuncAttributeMaxDynamicSharedMemorySize,
                              SMEM_BYTES);

    mamba_fused<<<B_SZ * 2, THREADS, SMEM_BYTES, stream>>>(
        x, buffer, fc_in_b, blk_norm_w, conv_w, conv_b,
        dt_bias, A_log, D_skip, mixer_norm_w, norm_f_w,
        fc_out_w, out_lin_w, out_y, out_buf);
}